// Round 11
// baseline (1245.732 us; speedup 1.0000x reference)
//
#pragma clang fp contract(off)
#include <hip/hip_runtime.h>
#include <math.h>

#define N_PTS   4096
#define B_SZ    8
#define NPOINT  1024
#define NSAMPLE 32
#define C_FEAT  128
#define C_IN    131
#define C_OUT   256
#define R2      1e-2f   // float(0.1*0.1) as JAX weak-casts it

#define KT      5       // K tiles of 32 (131 -> 160 padded)
#define NT      16      // N tiles of 16 (256)
#define KPAD    168     // LDS row stride in bf16 elems
#define NITEMS  (B_SZ * NPOINT)   // one item = one (b, s)
#define NWORK   136               // 8 fps + 128 worker blocks (120 CUs idle -> clock headroom)

typedef __attribute__((ext_vector_type(8))) short bf16x8;
typedef __attribute__((ext_vector_type(4))) float f32x4;
typedef __attribute__((ext_vector_type(2))) float v2f;

__device__ __forceinline__ unsigned short f2bf(float f) {   // RNE, matches hw cvt
    unsigned u = __float_as_uint(f);
    return (unsigned short)((u + 0x7FFF + ((u >> 16) & 1)) >> 16);
}
__device__ __forceinline__ float bf2f(unsigned short h) {
    return __uint_as_float(((unsigned)h) << 16);
}

// forced VOP3P packed fp32 (full-rate on CDNA4)
__device__ __forceinline__ v2f pk_add(v2f a, v2f b) {
    v2f d; asm("v_pk_add_f32 %0, %1, %2" : "=v"(d) : "v"(a), "v"(b)); return d;
}
__device__ __forceinline__ v2f pk_mul(v2f a, v2f b) {
    v2f d; asm("v_pk_mul_f32 %0, %1, %2" : "=v"(d) : "v"(a), "v"(b)); return d;
}

// raw workgroup barrier: drain LDS ops only — center stores stay in flight (no vmcnt(0))
#define LGKM_BARRIER() asm volatile("s_waitcnt lgkmcnt(0)\n\ts_barrier" ::: "memory")

// ---------------- K0: W split/swizzle + ctrl zeroing (stream-ordered before mega) ----
__global__ __launch_bounds__(64) void k_wtrans(const float* __restrict__ W,
                                               unsigned short* __restrict__ Wb_hi,
                                               unsigned short* __restrict__ Wb_lo,
                                               unsigned* __restrict__ ctrl) {
    if (blockIdx.x == 0 && threadIdx.x < 16) ctrl[threadIdx.x] = 0u;
    const int blk  = blockIdx.x;            // kt*NT + nt
    const int kt   = blk / NT, nt = blk % NT;
    const int lane = threadIdx.x;
    const int o    = nt * 16 + (lane & 15);
    const int k0   = kt * 32 + (lane >> 4) * 8;
    const size_t base = ((size_t)blk * 64 + lane) * 8;
#pragma unroll
    for (int j = 0; j < 8; ++j) {
        int k = k0 + j;
        float v = 0.0f;
        if (k < C_IN) {
            int src = (k < C_FEAT) ? (k + 3) : (k - C_FEAT);
            v = W[o * C_IN + src];
        }
        unsigned short hh = f2bf(v);
        Wb_hi[base + j] = hh;
        Wb_lo[base + j] = f2bf(v - bf2f(hh));
    }
}

// ---------------- FPS helpers (R7-proven) ----------------
#define FPS_BLOCK 256
#define FPS_PPT   16    // 8 float2 pairs per thread
#define FPS_NW    (FPS_BLOCK / 64)

#define DPP_ARGMAX(vb, vi, ctrl_, rmask)                                          \
    do {                                                                          \
        int _nb = __builtin_amdgcn_update_dpp(vb, vb, ctrl_, rmask, 0xf, false);  \
        int _ni = __builtin_amdgcn_update_dpp(vi, vi, ctrl_, rmask, 0xf, false);  \
        bool _g = (_nb >= vb);                                                    \
        vb = _g ? _nb : vb;                                                       \
        vi = _g ? _ni : vi;                                                       \
    } while (0)

#define CMB(ab, aj, bb_, bj_)                                                     \
    do {                                                                          \
        bool _g = ((bb_) > (ab));                                                 \
        ab = _g ? (bb_) : (ab);                                                   \
        aj = _g ? (bj_) : (aj);                                                   \
    } while (0)

__device__ __forceinline__ float bn_relu(float v, float mean, float scale, float beta) {
    float r = ((v - mean) * scale) + beta;
    return fmaxf(r, 0.0f);
}

// ---------------- MEGA kernel: fps (blocks 0-7) + pipelined bq+gemm workers ----------------
// smem layout (union by role):
//   fps:    xyzw float4[4096] @0 (65536), red u64[2][4] @65536, cstage float4[16] @65600
//   worker: Xh @0 (10752), Xl @10752, sc @21504, mn @22032, bt @22560,
//           idxs @23088 (32 int), nq @23216 (3 f), item @23232 (int)
// 84000 B total -> 1 block/CU.
__global__ __launch_bounds__(256) void k_mega(
    const float* __restrict__ xyz, const float* __restrict__ feat,
    const unsigned short* __restrict__ Wb_hi, const unsigned short* __restrict__ Wb_lo,
    const float* __restrict__ bias,
    const float* __restrict__ bn_g, const float* __restrict__ bn_b,
    const float* __restrict__ bn_m, const float* __restrict__ bn_v,
    float* new_xyz, float* __restrict__ out, unsigned* ctrl) {
    __shared__ char smem[84000];
    const int t    = threadIdx.x;
    const int lane = t & 63;
    const int wid  = t >> 6;

    if (blockIdx.x < B_SZ) {
        // ================= FPS role (raw lgkm barriers; wave0-local store drain) ========
        float4* xyzw = (float4*)smem;
        unsigned long long (*red)[FPS_NW] = (unsigned long long (*)[FPS_NW])(smem + 65536);
        float4* cstage = (float4*)(smem + 65600);
        const int b = blockIdx.x;
        const float* base = xyz + (size_t)b * N_PTS * 3;

        v2f nX[8], nY[8], nZ[8], M[8];
        const float4* b4 = (const float4*)(base + (size_t)t * (FPS_PPT * 3));
        float4 v[12];
#pragma unroll
        for (int i = 0; i < 12; ++i) v[i] = b4[i];
        const float* vf = (const float*)v;
#pragma unroll
        for (int p = 0; p < 8; ++p) {
            float x0 = vf[(2 * p) * 3 + 0], x1 = vf[(2 * p + 1) * 3 + 0];
            float y0 = vf[(2 * p) * 3 + 1], y1 = vf[(2 * p + 1) * 3 + 1];
            float z0 = vf[(2 * p) * 3 + 2], z1 = vf[(2 * p + 1) * 3 + 2];
            nX[p] = (v2f){-x0, -x1};
            nY[p] = (v2f){-y0, -y1};
            nZ[p] = (v2f){-z0, -z1};
            M[p]  = (v2f){1e10f, 1e10f};
            int gi = t * FPS_PPT + 2 * p;
            xyzw[gi]     = (float4){x0, y0, z0, 0.0f};
            xyzw[gi + 1] = (float4){x1, y1, z1, 0.0f};
        }
        __syncthreads();

        float4 c4 = xyzw[0];
        float cx = c4.x, cy = c4.y, cz = c4.z;
        if (t == 0) cstage[0] = c4;    // slot 0 of window 0 (s=0)

        for (int it = 1; it < NPOINT; ++it) {
            const v2f ccx = (v2f){cx, cx};
            const v2f ccy = (v2f){cy, cy};
            const v2f ccz = (v2f){cz, cz};
            int pb[8], pj[8];
#pragma unroll
            for (int p = 0; p < 8; ++p) {
                v2f dx = pk_add(nX[p], ccx);
                v2f dy = pk_add(nY[p], ccy);
                v2f dz = pk_add(nZ[p], ccz);
                v2f xx = pk_mul(dx, dx);
                v2f yy = pk_mul(dy, dy);
                v2f zz = pk_mul(dz, dz);
                v2f d  = pk_add(pk_add(xx, yy), zz);
                M[p].x = fminf(M[p].x, d.x);
                M[p].y = fminf(M[p].y, d.y);
                int bx = __float_as_int(M[p].x);
                int by = __float_as_int(M[p].y);
                bool g = by > bx;
                pb[p] = g ? by : bx;
                pj[p] = g ? (2 * p + 1) : (2 * p);
            }
            CMB(pb[0], pj[0], pb[1], pj[1]);
            CMB(pb[2], pj[2], pb[3], pj[3]);
            CMB(pb[4], pj[4], pb[5], pj[5]);
            CMB(pb[6], pj[6], pb[7], pj[7]);
            CMB(pb[0], pj[0], pb[2], pj[2]);
            CMB(pb[4], pj[4], pb[6], pj[6]);
            CMB(pb[0], pj[0], pb[4], pj[4]);
            int vb = pb[0];
            int vi = t * FPS_PPT + pj[0];
            DPP_ARGMAX(vb, vi, 0x111, 0xf);
            DPP_ARGMAX(vb, vi, 0x112, 0xf);
            DPP_ARGMAX(vb, vi, 0x114, 0xf);
            DPP_ARGMAX(vb, vi, 0x118, 0xf);
            DPP_ARGMAX(vb, vi, 0x142, 0xa);
            DPP_ARGMAX(vb, vi, 0x143, 0xc);
            if (lane == 63)
                red[it & 1][wid] = ((unsigned long long)(unsigned)vb << 32)
                                 | (unsigned)(N_PTS - 1 - vi);
            LGKM_BARRIER();                 // LDS-only drain: center stores stay in flight
            // publish: wave0's release waits ONLY wave0's vmcnt -> last window's store
            // (issued one iter ago, retired in background); stall, if any, is wave0-local
            if ((it & 15) == 0 && t == 0)
                __hip_atomic_store(&ctrl[b], (unsigned)it,
                                   __ATOMIC_RELEASE, __HIP_MEMORY_SCOPE_AGENT);
            const unsigned long long* rp = red[it & 1];
            unsigned long long k0 = rp[0], k1 = rp[1], k2 = rp[2], k3 = rp[3];
            unsigned long long b01 = k0 > k1 ? k0 : k1;
            unsigned long long b23 = k2 > k3 ? k2 : k3;
            unsigned long long best = b01 > b23 ? b01 : b23;
            const int idx = N_PTS - 1 - (int)(best & 0xFFFFull);
            float4 w4 = xyzw[idx];
            cx = w4.x; cy = w4.y; cz = w4.z;
            if (t == (it & 15)) cstage[it & 15] = w4;   // LDS stage (lane-local write)
            if ((it & 15) == 15 && t < 16) {            // one exec-masked store instr on wave0
                float4 c = cstage[t];
                float* o = new_xyz + ((size_t)b * NPOINT + (it - 15) + t) * 3;
                __hip_atomic_store(&o[0], c.x, __ATOMIC_RELAXED, __HIP_MEMORY_SCOPE_AGENT);
                __hip_atomic_store(&o[1], c.y, __ATOMIC_RELAXED, __HIP_MEMORY_SCOPE_AGENT);
                __hip_atomic_store(&o[2], c.z, __ATOMIC_RELAXED, __HIP_MEMORY_SCOPE_AGENT);
            }
        }
        __syncthreads();   // full drain (vm+lgkm) + LDS handoff to worker role
        if (t == 0)
            __hip_atomic_store(&ctrl[b], (unsigned)NPOINT,
                               __ATOMIC_RELEASE, __HIP_MEMORY_SCOPE_AGENT);
    }

    // ================= worker role (136 blocks; fps blocks join late) =================
    unsigned short (*Xh)[KPAD] = (unsigned short (*)[KPAD])smem;
    unsigned short (*Xl)[KPAD] = (unsigned short (*)[KPAD])(smem + 10752);
    float* sc_l = (float*)(smem + 21504);
    float* mn_l = (float*)(smem + 22032);
    float* bt_l = (float*)(smem + 22560);
    int*   idxs = (int*)(smem + 23088);
    float* nq   = (float*)(smem + 23216);
    int*   itsl = (int*)(smem + 23232);

    if (t < C_IN) {
        float g  = bn_g[t];
        float vv = bn_v[t] + 1e-5f;
        sc_l[t] = g / sqrtf(vv);
        mn_l[t] = bn_m[t];
        bt_l[t] = bn_b[t];
    }
    __syncthreads();

    for (;;) {
        if (t == 0) *itsl = (int)atomicAdd(&ctrl[8], 1u);   // dynamic claim: deadlock-free
        __syncthreads();
        const int item = *itsl;
        if (item >= NITEMS) break;
        const int s  = item >> 3;       // s ascending over claims -> matches fps production
        const int bb = item & 7;
        if (t == 0) {
            while ((int)__hip_atomic_load(&ctrl[bb], __ATOMIC_RELAXED,
                                          __HIP_MEMORY_SCOPE_AGENT) < s + 1)
                __builtin_amdgcn_s_sleep(32);
        }
        __syncthreads();

        // ---- ball query for (bb, s): wave 0, first NSAMPLE in index order ----
        if (wid == 0) {
            float* qp = new_xyz + ((size_t)bb * NPOINT + s) * 3;
            float qx = __hip_atomic_load(&qp[0], __ATOMIC_RELAXED, __HIP_MEMORY_SCOPE_AGENT);
            float qy = __hip_atomic_load(&qp[1], __ATOMIC_RELAXED, __HIP_MEMORY_SCOPE_AGENT);
            float qz = __hip_atomic_load(&qp[2], __ATOMIC_RELAXED, __HIP_MEMORY_SCOPE_AGENT);
            if (lane == 0) { nq[0] = qx; nq[1] = qy; nq[2] = qz; }
            const float* xb = xyz + (size_t)bb * N_PTS * 3;
            int total = 0, first = -1;
            const unsigned long long mlt = (1ull << lane) - 1ull;
            for (int ch = 0; ch < N_PTS / 64; ++ch) {
                int i2 = ch * 64 + lane;
                float x = xb[i2 * 3 + 0], y = xb[i2 * 3 + 1], z = xb[i2 * 3 + 2];
                float dx = qx - x, dy = qy - y, dz = qz - z;
                float d2 = ((dx * dx) + (dy * dy)) + (dz * dz);
                bool valid = d2 < R2;
                unsigned long long m = __ballot(valid);
                if (valid) {
                    int pos = total + __popcll(m & mlt);
                    if (pos < NSAMPLE) idxs[pos] = i2;
                }
                if (first < 0 && m != 0ull) first = ch * 64 + (__ffsll(m) - 1);
                total += __popcll(m);
                if (total >= NSAMPLE) break;
            }
            if (total < NSAMPLE) {
                if (lane >= total && lane < NSAMPLE) idxs[lane] = first;
            }
        }
        __syncthreads();

        // ---- stage x tile (bf16 hi/lo) ----
        {
            const int ks = t & 31;
            const int qh = t >> 5;
            const float* frow = feat + ((size_t)bb * N_PTS + idxs[ks]) * C_FEAT;
#pragma unroll
            for (int m2 = 0; m2 < 4; ++m2) {
                int qq = m2 * 8 + qh;
                int c0 = qq * 4;
                float4 f = *(const float4*)&frow[c0];
                float v0 = bn_relu(f.x, mn_l[3 + c0 + 0], sc_l[3 + c0 + 0], bt_l[3 + c0 + 0]);
                float v1 = bn_relu(f.y, mn_l[3 + c0 + 1], sc_l[3 + c0 + 1], bt_l[3 + c0 + 1]);
                float v2 = bn_relu(f.z, mn_l[3 + c0 + 2], sc_l[3 + c0 + 2], bt_l[3 + c0 + 2]);
                float v3 = bn_relu(f.w, mn_l[3 + c0 + 3], sc_l[3 + c0 + 3], bt_l[3 + c0 + 3]);
                unsigned short h0 = f2bf(v0), h1 = f2bf(v1), h2 = f2bf(v2), h3 = f2bf(v3);
                uint2 hv, lv;
                hv.x = (unsigned)h0 | ((unsigned)h1 << 16);
                hv.y = (unsigned)h2 | ((unsigned)h3 << 16);
                lv.x = (unsigned)f2bf(v0 - bf2f(h0)) | ((unsigned)f2bf(v1 - bf2f(h1)) << 16);
                lv.y = (unsigned)f2bf(v2 - bf2f(h2)) | ((unsigned)f2bf(v3 - bf2f(h3)) << 16);
                *(uint2*)&Xh[ks][c0] = hv;
                *(uint2*)&Xl[ks][c0] = lv;
            }
        }
        if (t < 32) {
            const int row = t;
            const int id  = idxs[row];
            const float* p = xyz + ((size_t)bb * N_PTS + id) * 3;
            uint4 z4 = {0u, 0u, 0u, 0u};
            uint4 hh = z4, ll = z4;
            unsigned short h[3];
#pragma unroll
            for (int d = 0; d < 3; ++d) {
                float g = p[d] - nq[d];
                float vv = bn_relu(g, mn_l[d], sc_l[d], bt_l[d]);
                h[d] = f2bf(vv);
                unsigned short lo = f2bf(vv - bf2f(h[d]));
                if (d == 0) { hh.x |= h[d];                 ll.x |= lo; }
                if (d == 1) { hh.x |= (unsigned)h[d] << 16; ll.x |= (unsigned)lo << 16; }
                if (d == 2) { hh.y |= h[d];                 ll.y |= lo; }
            }
            *(uint4*)&Xh[row][128] = hh;  *(uint4*)&Xl[row][128] = ll;
            *(uint4*)&Xh[row][136] = z4;  *(uint4*)&Xl[row][136] = z4;
            *(uint4*)&Xh[row][144] = z4;  *(uint4*)&Xl[row][144] = z4;
            *(uint4*)&Xh[row][152] = z4;  *(uint4*)&Xl[row][152] = z4;
            *(uint4*)&Xh[row][160] = z4;  *(uint4*)&Xl[row][160] = z4;
        }
        __syncthreads();

        // ---- split-bf16 MFMA GEMM + max epilogue ----
        f32x4 zero = {0.f, 0.f, 0.f, 0.f};
        f32x4 acc[2][4];
#pragma unroll
        for (int m2 = 0; m2 < 2; ++m2)
#pragma unroll
            for (int n = 0; n < 4; ++n) acc[m2][n] = zero;

        const int r0 = lane & 15;
#pragma unroll
        for (int kt = 0; kt < KT; ++kt) {
            const int k0 = kt * 32 + (lane >> 4) * 8;
            bf16x8 a0h = *(const bf16x8*)&Xh[r0][k0];
            bf16x8 a1h = *(const bf16x8*)&Xh[16 + r0][k0];
            bf16x8 a0l = *(const bf16x8*)&Xl[r0][k0];
            bf16x8 a1l = *(const bf16x8*)&Xl[16 + r0][k0];
#pragma unroll
            for (int n = 0; n < 4; ++n) {
                const int nt = wid * 4 + n;
                const size_t off = (((size_t)kt * NT + nt) * 64 + lane) * 8;
                bf16x8 bh = *(const bf16x8*)&Wb_hi[off];
                bf16x8 bl = *(const bf16x8*)&Wb_lo[off];
                acc[0][n] = __builtin_amdgcn_mfma_f32_16x16x32_bf16(a0h, bh, acc[0][n], 0, 0, 0);
                acc[1][n] = __builtin_amdgcn_mfma_f32_16x16x32_bf16(a1h, bh, acc[1][n], 0, 0, 0);
                acc[0][n] = __builtin_amdgcn_mfma_f32_16x16x32_bf16(a0l, bh, acc[0][n], 0, 0, 0);
                acc[1][n] = __builtin_amdgcn_mfma_f32_16x16x32_bf16(a1l, bh, acc[1][n], 0, 0, 0);
                acc[0][n] = __builtin_amdgcn_mfma_f32_16x16x32_bf16(a0h, bl, acc[0][n], 0, 0, 0);
                acc[1][n] = __builtin_amdgcn_mfma_f32_16x16x32_bf16(a1h, bl, acc[1][n], 0, 0, 0);
            }
        }

#pragma unroll
        for (int n = 0; n < 4; ++n) {
            float m0 = fmaxf(acc[0][n][0], acc[1][n][0]);
            float m1 = fmaxf(acc[0][n][1], acc[1][n][1]);
            float m2 = fmaxf(acc[0][n][2], acc[1][n][2]);
            float m3 = fmaxf(acc[0][n][3], acc[1][n][3]);
            float pm = fmaxf(fmaxf(m0, m1), fmaxf(m2, m3));
            pm = fmaxf(pm, __shfl_xor(pm, 16));
            pm = fmaxf(pm, __shfl_xor(pm, 32));
            if (lane < 16) {
                int o = (wid * 4 + n) * 16 + lane;
                out[(size_t)bb * C_OUT * NPOINT + (size_t)o * NPOINT + s] = pm + bias[o];
            }
        }
        // next claim's barrier protects LDS reuse
    }
}

extern "C" void kernel_launch(void* const* d_in, const int* in_sizes, int n_in,
                              void* d_out, int out_size, void* d_ws, size_t ws_size,
                              hipStream_t stream) {
    const float* xyz  = (const float*)d_in[0];
    const float* feat = (const float*)d_in[1];
    const float* W    = (const float*)d_in[2];
    const float* bias = (const float*)d_in[3];
    const float* bn_g = (const float*)d_in[4];
    const float* bn_b = (const float*)d_in[5];
    const float* bn_m = (const float*)d_in[6];
    const float* bn_v = (const float*)d_in[7];

    float* new_xyz  = (float*)d_out;                                   // (8,1024,3)
    float* out_feat = (float*)d_out + (size_t)B_SZ * NPOINT * 3;       // (8,256,1024)

    unsigned short* Wb_hi = (unsigned short*)d_ws;                     // 81920 B
    unsigned short* Wb_lo = Wb_hi + (size_t)KT * NT * 64 * 8;          // 81920 B
    unsigned*       ctrl  = (unsigned*)((char*)d_ws + 163840);         // flags[8] + cursor

    hipLaunchKernelGGL(k_wtrans, dim3(KT * NT), dim3(64), 0, stream, W, Wb_hi, Wb_lo, ctrl);
    hipLaunchKernelGGL(k_mega,   dim3(NWORK),   dim3(256), 0, stream,
                       xyz, feat, Wb_hi, Wb_lo, bias,
                       bn_g, bn_b, bn_m, bn_v, new_xyz, out_feat, ctrl);
}

// Round 12
// 806.430 us; speedup vs baseline: 1.5447x; 1.5447x over previous
//
#pragma clang fp contract(off)
#include <hip/hip_runtime.h>
#include <math.h>

#define N_PTS   4096
#define B_SZ    8
#define NPOINT  1024
#define NSAMPLE 32
#define C_FEAT  128
#define C_IN    131
#define C_OUT   256
#define R2      1e-2f   // float(0.1*0.1) as JAX weak-casts it

#define KT      5       // K tiles of 32 (131 -> 160 padded)
#define NT      16      // N tiles of 16 (256)
#define KPAD    168     // LDS row stride in bf16 elems
#define NITEMS  (B_SZ * NPOINT)   // one item = one (b, s)
#define NWORK   256               // 8 fps + 248 workers (R11: 128 workers = worker-bound, fatal)

typedef __attribute__((ext_vector_type(8))) short bf16x8;
typedef __attribute__((ext_vector_type(4))) float f32x4;
typedef __attribute__((ext_vector_type(2))) float v2f;

__device__ __forceinline__ unsigned short f2bf(float f) {   // RNE, matches hw cvt
    unsigned u = __float_as_uint(f);
    return (unsigned short)((u + 0x7FFF + ((u >> 16) & 1)) >> 16);
}
__device__ __forceinline__ float bf2f(unsigned short h) {
    return __uint_as_float(((unsigned)h) << 16);
}

// forced VOP3P packed fp32 (full-rate on CDNA4)
__device__ __forceinline__ v2f pk_add(v2f a, v2f b) {
    v2f d; asm("v_pk_add_f32 %0, %1, %2" : "=v"(d) : "v"(a), "v"(b)); return d;
}
__device__ __forceinline__ v2f pk_mul(v2f a, v2f b) {
    v2f d; asm("v_pk_mul_f32 %0, %1, %2" : "=v"(d) : "v"(a), "v"(b)); return d;
}

// raw workgroup barrier: drain LDS ops only — center stores stay in flight (no vmcnt(0))
#define LGKM_BARRIER() asm volatile("s_waitcnt lgkmcnt(0)\n\ts_barrier" ::: "memory")

// ---------------- K0: W split/swizzle + ctrl zeroing (stream-ordered before mega) ----
__global__ __launch_bounds__(64) void k_wtrans(const float* __restrict__ W,
                                               unsigned short* __restrict__ Wb_hi,
                                               unsigned short* __restrict__ Wb_lo,
                                               unsigned* __restrict__ ctrl) {
    if (blockIdx.x == 0 && threadIdx.x < 16) ctrl[threadIdx.x] = 0u;
    const int blk  = blockIdx.x;            // kt*NT + nt
    const int kt   = blk / NT, nt = blk % NT;
    const int lane = threadIdx.x;
    const int o    = nt * 16 + (lane & 15);
    const int k0   = kt * 32 + (lane >> 4) * 8;
    const size_t base = ((size_t)blk * 64 + lane) * 8;
#pragma unroll
    for (int j = 0; j < 8; ++j) {
        int k = k0 + j;
        float v = 0.0f;
        if (k < C_IN) {
            int src = (k < C_FEAT) ? (k + 3) : (k - C_FEAT);
            v = W[o * C_IN + src];
        }
        unsigned short hh = f2bf(v);
        Wb_hi[base + j] = hh;
        Wb_lo[base + j] = f2bf(v - bf2f(hh));
    }
}

// ---------------- FPS helpers (R7-proven) ----------------
#define FPS_BLOCK 256
#define FPS_PPT   16    // 8 float2 pairs per thread
#define FPS_NW    (FPS_BLOCK / 64)

#define DPP_ARGMAX(vb, vi, ctrl_, rmask)                                          \
    do {                                                                          \
        int _nb = __builtin_amdgcn_update_dpp(vb, vb, ctrl_, rmask, 0xf, false);  \
        int _ni = __builtin_amdgcn_update_dpp(vi, vi, ctrl_, rmask, 0xf, false);  \
        bool _g = (_nb >= vb);                                                    \
        vb = _g ? _nb : vb;                                                       \
        vi = _g ? _ni : vi;                                                       \
    } while (0)

#define CMB(ab, aj, bb_, bj_)                                                     \
    do {                                                                          \
        bool _g = ((bb_) > (ab));                                                 \
        ab = _g ? (bb_) : (ab);                                                   \
        aj = _g ? (bj_) : (aj);                                                   \
    } while (0)

__device__ __forceinline__ float bn_relu(float v, float mean, float scale, float beta) {
    float r = ((v - mean) * scale) + beta;
    return fmaxf(r, 0.0f);
}

// ---------------- MEGA kernel: fps (blocks 0-7) + pipelined bq+gemm workers ----------------
// smem layout (union by role):
//   fps:    xyzw float4[4096] @0 (65536), red u64[2][4] @65536, cstage float4[16] @65600
//   worker: Xh @0 (10752), Xl @10752, sc @21504, mn @22032, bt @22560,
//           idxs @23088 (32 int), nq @23216 (3 f), itsl @23232, masks u64[64] @23240
// 84000 B total -> 1 block/CU.
__global__ __launch_bounds__(256) void k_mega(
    const float* __restrict__ xyz, const float* __restrict__ feat,
    const unsigned short* __restrict__ Wb_hi, const unsigned short* __restrict__ Wb_lo,
    const float* __restrict__ bias,
    const float* __restrict__ bn_g, const float* __restrict__ bn_b,
    const float* __restrict__ bn_m, const float* __restrict__ bn_v,
    float* new_xyz, float* __restrict__ out, unsigned* ctrl) {
    __shared__ char smem[84000];
    const int t    = threadIdx.x;
    const int lane = t & 63;
    const int wid  = t >> 6;

    if (blockIdx.x < B_SZ) {
        // ================= FPS role (raw lgkm barriers; wave0-local store drain) ========
        float4* xyzw = (float4*)smem;
        unsigned long long (*red)[FPS_NW] = (unsigned long long (*)[FPS_NW])(smem + 65536);
        float4* cstage = (float4*)(smem + 65600);
        const int b = blockIdx.x;
        const float* base = xyz + (size_t)b * N_PTS * 3;

        v2f nX[8], nY[8], nZ[8], M[8];
        const float4* b4 = (const float4*)(base + (size_t)t * (FPS_PPT * 3));
        float4 v[12];
#pragma unroll
        for (int i = 0; i < 12; ++i) v[i] = b4[i];
        const float* vf = (const float*)v;
#pragma unroll
        for (int p = 0; p < 8; ++p) {
            float x0 = vf[(2 * p) * 3 + 0], x1 = vf[(2 * p + 1) * 3 + 0];
            float y0 = vf[(2 * p) * 3 + 1], y1 = vf[(2 * p + 1) * 3 + 1];
            float z0 = vf[(2 * p) * 3 + 2], z1 = vf[(2 * p + 1) * 3 + 2];
            nX[p] = (v2f){-x0, -x1};
            nY[p] = (v2f){-y0, -y1};
            nZ[p] = (v2f){-z0, -z1};
            M[p]  = (v2f){1e10f, 1e10f};
            int gi = t * FPS_PPT + 2 * p;
            xyzw[gi]     = (float4){x0, y0, z0, 0.0f};
            xyzw[gi + 1] = (float4){x1, y1, z1, 0.0f};
        }
        __syncthreads();

        float4 c4 = xyzw[0];
        float cx = c4.x, cy = c4.y, cz = c4.z;
        if (t == 0) cstage[0] = c4;    // slot 0 of window 0 (s=0)

        for (int it = 1; it < NPOINT; ++it) {
            const v2f ccx = (v2f){cx, cx};
            const v2f ccy = (v2f){cy, cy};
            const v2f ccz = (v2f){cz, cz};
            int pb[8], pj[8];
#pragma unroll
            for (int p = 0; p < 8; ++p) {
                v2f dx = pk_add(nX[p], ccx);
                v2f dy = pk_add(nY[p], ccy);
                v2f dz = pk_add(nZ[p], ccz);
                v2f xx = pk_mul(dx, dx);
                v2f yy = pk_mul(dy, dy);
                v2f zz = pk_mul(dz, dz);
                v2f d  = pk_add(pk_add(xx, yy), zz);
                M[p].x = fminf(M[p].x, d.x);
                M[p].y = fminf(M[p].y, d.y);
                int bx = __float_as_int(M[p].x);
                int by = __float_as_int(M[p].y);
                bool g = by > bx;
                pb[p] = g ? by : bx;
                pj[p] = g ? (2 * p + 1) : (2 * p);
            }
            CMB(pb[0], pj[0], pb[1], pj[1]);
            CMB(pb[2], pj[2], pb[3], pj[3]);
            CMB(pb[4], pj[4], pb[5], pj[5]);
            CMB(pb[6], pj[6], pb[7], pj[7]);
            CMB(pb[0], pj[0], pb[2], pj[2]);
            CMB(pb[4], pj[4], pb[6], pj[6]);
            CMB(pb[0], pj[0], pb[4], pj[4]);
            int vb = pb[0];
            int vi = t * FPS_PPT + pj[0];
            DPP_ARGMAX(vb, vi, 0x111, 0xf);
            DPP_ARGMAX(vb, vi, 0x112, 0xf);
            DPP_ARGMAX(vb, vi, 0x114, 0xf);
            DPP_ARGMAX(vb, vi, 0x118, 0xf);
            DPP_ARGMAX(vb, vi, 0x142, 0xa);
            DPP_ARGMAX(vb, vi, 0x143, 0xc);
            if (lane == 63)
                red[it & 1][wid] = ((unsigned long long)(unsigned)vb << 32)
                                 | (unsigned)(N_PTS - 1 - vi);
            LGKM_BARRIER();                 // LDS-only drain: center stores stay in flight
            if ((it & 15) == 0 && t == 0)
                __hip_atomic_store(&ctrl[b], (unsigned)it,
                                   __ATOMIC_RELEASE, __HIP_MEMORY_SCOPE_AGENT);
            const unsigned long long* rp = red[it & 1];
            unsigned long long k0 = rp[0], k1 = rp[1], k2 = rp[2], k3 = rp[3];
            unsigned long long b01 = k0 > k1 ? k0 : k1;
            unsigned long long b23 = k2 > k3 ? k2 : k3;
            unsigned long long best = b01 > b23 ? b01 : b23;
            const int idx = N_PTS - 1 - (int)(best & 0xFFFFull);
            float4 w4 = xyzw[idx];
            cx = w4.x; cy = w4.y; cz = w4.z;
            if (t == (it & 15)) cstage[it & 15] = w4;   // LDS stage (lane-local write)
            if ((it & 15) == 15 && t < 16) {            // one exec-masked store instr on wave0
                float4 c = cstage[t];
                float* o = new_xyz + ((size_t)b * NPOINT + (it - 15) + t) * 3;
                __hip_atomic_store(&o[0], c.x, __ATOMIC_RELAXED, __HIP_MEMORY_SCOPE_AGENT);
                __hip_atomic_store(&o[1], c.y, __ATOMIC_RELAXED, __HIP_MEMORY_SCOPE_AGENT);
                __hip_atomic_store(&o[2], c.z, __ATOMIC_RELAXED, __HIP_MEMORY_SCOPE_AGENT);
            }
        }
        __syncthreads();   // full drain (vm+lgkm) + LDS handoff to worker role
        if (t == 0)
            __hip_atomic_store(&ctrl[b], (unsigned)NPOINT,
                               __ATOMIC_RELEASE, __HIP_MEMORY_SCOPE_AGENT);
    }

    // ================= worker role (all 256 blocks; fps blocks join late) =================
    unsigned short (*Xh)[KPAD] = (unsigned short (*)[KPAD])smem;
    unsigned short (*Xl)[KPAD] = (unsigned short (*)[KPAD])(smem + 10752);
    float* sc_l = (float*)(smem + 21504);
    float* mn_l = (float*)(smem + 22032);
    float* bt_l = (float*)(smem + 22560);
    int*   idxs = (int*)(smem + 23088);
    float* nq   = (float*)(smem + 23216);
    int*   itsl = (int*)(smem + 23232);
    unsigned long long* masks = (unsigned long long*)(smem + 23240);

    if (t < C_IN) {
        float g  = bn_g[t];
        float vv = bn_v[t] + 1e-5f;
        sc_l[t] = g / sqrtf(vv);
        mn_l[t] = bn_m[t];
        bt_l[t] = bn_b[t];
    }
    __syncthreads();

    for (;;) {
        if (t == 0) *itsl = (int)atomicAdd(&ctrl[8], 1u);   // dynamic claim: deadlock-free
        __syncthreads();
        const int item = *itsl;
        if (item >= NITEMS) break;
        const int s  = item >> 3;       // s ascending over claims -> matches fps production
        const int bb = item & 7;
        if (t == 0) {
            while ((int)__hip_atomic_load(&ctrl[bb], __ATOMIC_RELAXED,
                                          __HIP_MEMORY_SCOPE_AGENT) < s + 1)
                __builtin_amdgcn_s_sleep(32);
            float* qp = new_xyz + ((size_t)bb * NPOINT + s) * 3;
            nq[0] = __hip_atomic_load(&qp[0], __ATOMIC_RELAXED, __HIP_MEMORY_SCOPE_AGENT);
            nq[1] = __hip_atomic_load(&qp[1], __ATOMIC_RELAXED, __HIP_MEMORY_SCOPE_AGENT);
            nq[2] = __hip_atomic_load(&qp[2], __ATOMIC_RELAXED, __HIP_MEMORY_SCOPE_AGENT);
        }
        __syncthreads();

        // ---- ball query (bb, s): 4 waves scan 16 chunks each -> masks; wave0 selects ----
        {
            const float qx = nq[0], qy = nq[1], qz = nq[2];
            const float* xb = xyz + (size_t)bb * N_PTS * 3;
#pragma unroll
            for (int c8 = 0; c8 < 16; ++c8) {
                int ch = wid * 16 + c8;
                int i2 = ch * 64 + lane;
                float x = xb[i2 * 3 + 0], y = xb[i2 * 3 + 1], z = xb[i2 * 3 + 2];
                float dx = qx - x, dy = qy - y, dz = qz - z;
                float d2 = ((dx * dx) + (dy * dy)) + (dz * dz);
                unsigned long long m = __ballot(d2 < R2);
                if (lane == 0) masks[ch] = m;
            }
        }
        __syncthreads();
        if (wid == 0) {
            // lane == chunk: ordered first-32 selection via prefix-sum scatter
            unsigned long long m = masks[lane];
            int cnt  = __popcll(m);
            int incl = cnt;
#pragma unroll
            for (int off = 1; off < 64; off <<= 1) {
                int y = __shfl_up(incl, off);
                if (lane >= off) incl += y;
            }
            int start = incl - cnt;
            int total = __shfl(incl, 63);
            int pos = start;
            unsigned long long mm = m;
            while (mm && pos < NSAMPLE) {           // bits in ffs order = index order
                int j = __ffsll(mm) - 1;
                idxs[pos++] = lane * 64 + j;
                mm &= mm - 1;
            }
            if (total < NSAMPLE) {                  // total >= 1 (center is in its own ball)
                unsigned long long nz = __ballot(m != 0ull);
                int fl = __ffsll(nz) - 1;
                unsigned long long fm = masks[fl];
                int first = fl * 64 + (__ffsll(fm) - 1);
                if (lane >= total && lane < NSAMPLE) idxs[lane] = first;
            }
        }
        __syncthreads();

        // ---- stage x tile (bf16 hi/lo) ----
        {
            const int ks = t & 31;
            const int qh = t >> 5;
            const float* frow = feat + ((size_t)bb * N_PTS + idxs[ks]) * C_FEAT;
#pragma unroll
            for (int m2 = 0; m2 < 4; ++m2) {
                int qq = m2 * 8 + qh;
                int c0 = qq * 4;
                float4 f = *(const float4*)&frow[c0];
                float v0 = bn_relu(f.x, mn_l[3 + c0 + 0], sc_l[3 + c0 + 0], bt_l[3 + c0 + 0]);
                float v1 = bn_relu(f.y, mn_l[3 + c0 + 1], sc_l[3 + c0 + 1], bt_l[3 + c0 + 1]);
                float v2 = bn_relu(f.z, mn_l[3 + c0 + 2], sc_l[3 + c0 + 2], bt_l[3 + c0 + 2]);
                float v3 = bn_relu(f.w, mn_l[3 + c0 + 3], sc_l[3 + c0 + 3], bt_l[3 + c0 + 3]);
                unsigned short h0 = f2bf(v0), h1 = f2bf(v1), h2 = f2bf(v2), h3 = f2bf(v3);
                uint2 hv, lv;
                hv.x = (unsigned)h0 | ((unsigned)h1 << 16);
                hv.y = (unsigned)h2 | ((unsigned)h3 << 16);
                lv.x = (unsigned)f2bf(v0 - bf2f(h0)) | ((unsigned)f2bf(v1 - bf2f(h1)) << 16);
                lv.y = (unsigned)f2bf(v2 - bf2f(h2)) | ((unsigned)f2bf(v3 - bf2f(h3)) << 16);
                *(uint2*)&Xh[ks][c0] = hv;
                *(uint2*)&Xl[ks][c0] = lv;
            }
        }
        if (t < 32) {
            const int row = t;
            const int id  = idxs[row];
            const float* p = xyz + ((size_t)bb * N_PTS + id) * 3;
            uint4 z4 = {0u, 0u, 0u, 0u};
            uint4 hh = z4, ll = z4;
            unsigned short h[3];
#pragma unroll
            for (int d = 0; d < 3; ++d) {
                float g = p[d] - nq[d];
                float vv = bn_relu(g, mn_l[d], sc_l[d], bt_l[d]);
                h[d] = f2bf(vv);
                unsigned short lo = f2bf(vv - bf2f(h[d]));
                if (d == 0) { hh.x |= h[d];                 ll.x |= lo; }
                if (d == 1) { hh.x |= (unsigned)h[d] << 16; ll.x |= (unsigned)lo << 16; }
                if (d == 2) { hh.y |= h[d];                 ll.y |= lo; }
            }
            *(uint4*)&Xh[row][128] = hh;  *(uint4*)&Xl[row][128] = ll;
            *(uint4*)&Xh[row][136] = z4;  *(uint4*)&Xl[row][136] = z4;
            *(uint4*)&Xh[row][144] = z4;  *(uint4*)&Xl[row][144] = z4;
            *(uint4*)&Xh[row][152] = z4;  *(uint4*)&Xl[row][152] = z4;
            *(uint4*)&Xh[row][160] = z4;  *(uint4*)&Xl[row][160] = z4;
        }
        __syncthreads();

        // ---- split-bf16 MFMA GEMM + max epilogue ----
        f32x4 zero = {0.f, 0.f, 0.f, 0.f};
        f32x4 acc[2][4];
#pragma unroll
        for (int m2 = 0; m2 < 2; ++m2)
#pragma unroll
            for (int n = 0; n < 4; ++n) acc[m2][n] = zero;

        const int r0 = lane & 15;
#pragma unroll
        for (int kt = 0; kt < KT; ++kt) {
            const int k0 = kt * 32 + (lane >> 4) * 8;
            bf16x8 a0h = *(const bf16x8*)&Xh[r0][k0];
            bf16x8 a1h = *(const bf16x8*)&Xh[16 + r0][k0];
            bf16x8 a0l = *(const bf16x8*)&Xl[r0][k0];
            bf16x8 a1l = *(const bf16x8*)&Xl[16 + r0][k0];
#pragma unroll
            for (int n = 0; n < 4; ++n) {
                const int nt = wid * 4 + n;
                const size_t off = (((size_t)kt * NT + nt) * 64 + lane) * 8;
                bf16x8 bh = *(const bf16x8*)&Wb_hi[off];
                bf16x8 bl = *(const bf16x8*)&Wb_lo[off];
                acc[0][n] = __builtin_amdgcn_mfma_f32_16x16x32_bf16(a0h, bh, acc[0][n], 0, 0, 0);
                acc[1][n] = __builtin_amdgcn_mfma_f32_16x16x32_bf16(a1h, bh, acc[1][n], 0, 0, 0);
                acc[0][n] = __builtin_amdgcn_mfma_f32_16x16x32_bf16(a0l, bh, acc[0][n], 0, 0, 0);
                acc[1][n] = __builtin_amdgcn_mfma_f32_16x16x32_bf16(a1l, bh, acc[1][n], 0, 0, 0);
                acc[0][n] = __builtin_amdgcn_mfma_f32_16x16x32_bf16(a0h, bl, acc[0][n], 0, 0, 0);
                acc[1][n] = __builtin_amdgcn_mfma_f32_16x16x32_bf16(a1h, bl, acc[1][n], 0, 0, 0);
            }
        }

#pragma unroll
        for (int n = 0; n < 4; ++n) {
            float m0 = fmaxf(acc[0][n][0], acc[1][n][0]);
            float m1 = fmaxf(acc[0][n][1], acc[1][n][1]);
            float m2 = fmaxf(acc[0][n][2], acc[1][n][2]);
            float m3 = fmaxf(acc[0][n][3], acc[1][n][3]);
            float pm = fmaxf(fmaxf(m0, m1), fmaxf(m2, m3));
            pm = fmaxf(pm, __shfl_xor(pm, 16));
            pm = fmaxf(pm, __shfl_xor(pm, 32));
            if (lane < 16) {
                int o = (wid * 4 + n) * 16 + lane;
                out[(size_t)bb * C_OUT * NPOINT + (size_t)o * NPOINT + s] = pm + bias[o];
            }
        }
        // next claim's barrier protects LDS reuse
    }
}

extern "C" void kernel_launch(void* const* d_in, const int* in_sizes, int n_in,
                              void* d_out, int out_size, void* d_ws, size_t ws_size,
                              hipStream_t stream) {
    const float* xyz  = (const float*)d_in[0];
    const float* feat = (const float*)d_in[1];
    const float* W    = (const float*)d_in[2];
    const float* bias = (const float*)d_in[3];
    const float* bn_g = (const float*)d_in[4];
    const float* bn_b = (const float*)d_in[5];
    const float* bn_m = (const float*)d_in[6];
    const float* bn_v = (const float*)d_in[7];

    float* new_xyz  = (float*)d_out;                                   // (8,1024,3)
    float* out_feat = (float*)d_out + (size_t)B_SZ * NPOINT * 3;       // (8,256,1024)

    unsigned short* Wb_hi = (unsigned short*)d_ws;                     // 81920 B
    unsigned short* Wb_lo = Wb_hi + (size_t)KT * NT * 64 * 8;          // 81920 B
    unsigned*       ctrl  = (unsigned*)((char*)d_ws + 163840);         // flags[8] + cursor

    hipLaunchKernelGGL(k_wtrans, dim3(KT * NT), dim3(64), 0, stream, W, Wb_hi, Wb_lo, ctrl);
    hipLaunchKernelGGL(k_mega,   dim3(NWORK),   dim3(256), 0, stream,
                       xyz, feat, Wb_hi, Wb_lo, bias,
                       bn_g, bn_b, bn_m, bn_v, new_xyz, out_feat, ctrl);
}